// Round 3
// baseline (358.640 us; speedup 1.0000x reference)
//
#include <hip/hip_runtime.h>

// GCN 3-layer: N=50000, E=1.6M, D_IN=256, H=128, D_OUT=64, fp32 in/out.
// Round 12: bucketed counting sort killed the global-atomic wall (confirmed
// ~17G/s returning-atomic ceiling; fix was COUNT reduction).
// Round 13: SpMM gather is now 40% of runtime (58us x2 + 28us), bound by
// random-gather L2-miss refill (~3.2 TB/s pattern ceiling, FETCH 157MB vs
// 20MB ideal). Can't cheaply fix the gather; instead FUSE the layer GEMMs
// into the SpMM epilogue to delete gemm2/gemm3 + the Hf fp32 round-trip
// (51MB x2) entirely:
//   spmm_gemm: each block aggregates 32 nodes (4 waves x 8, dual-node MLP
//   chains), stores relu'd fp32 rows to LDS [32][132] (pad -> 2-way alias,
//   free), then 4 waves do 32x128 @ 128xF MFMA (same wprep fragment layout
//   + hi/lo split as gemm_mfma_dev), writing dinv-scaled bf16 T directly.
//   MFMA rides in the gather's shadow (MfmaUtil was 0).
// Pipeline: initprep -> bin -> scan -> fusedA2[gemm1|scatter] -> csr ->
//   spmm_gemm<128,GD> -> spmm_gemm<64> -> spmm<64> = 7 launches (was 9).
// Requires n <= 65536 (16-bit packing; harness n = 50000).

constexpr int DIN = 256;
constexpr int HID = 128;
constexpr int DOUT = 64;
constexpr int MAXB = 1024;   // max buckets (n <= 65536)
constexpr int BSH = 6;       // 64 nodes per bucket
constexpr int EPB = 8192;    // edges per bin/scatter block

typedef unsigned short ushort_t;
typedef unsigned int uint_t;
typedef __attribute__((ext_vector_type(8))) short bf16x8;
typedef __attribute__((ext_vector_type(4))) float f32x4;

__device__ inline ushort_t f2bf(float f) {
  uint_t u = __float_as_uint(f);
  u += 0x7FFF + ((u >> 16) & 1);  // RNE
  return (ushort_t)(u >> 16);
}
__device__ inline float bf2f(ushort_t b) {
  return __uint_as_float(((uint_t)b) << 16);
}

// ---------- weight prep (device fn): W[K][F] fp32 -> fragment bf16 hi/lo ----------
// Layout: Bp[t = n/16][s = k/32][lane = (k/8 % 4)*16 + n%16][j = k%8]

__device__ inline void wprep_one(const float* __restrict__ W, ushort_t* __restrict__ Bhi,
                                 ushort_t* __restrict__ Blo, int K, int F, int i) {
  int k = i / F, nn = i % F;
  int t = nn >> 4, s = k >> 5, q = (k >> 3) & 3, j = k & 7;
  int lane = q * 16 + (nn & 15);
  int KS = K >> 5;
  size_t idx = (((size_t)t * KS + s) * 64 + (size_t)lane) * 8 + j;
  float w = W[i];
  ushort_t h = f2bf(w);
  float r = w - bf2f(h);
  Bhi[idx] = h;
  Blo[idx] = f2bf(r);
}

// ---------- init: zero bucket_total + wprep x3 ----------

__global__ __launch_bounds__(256) void initprep_kernel(
    int* __restrict__ bucket_total, int iblocks,
    const float* __restrict__ W1, ushort_t* __restrict__ W1hi, ushort_t* __restrict__ W1lo,
    const float* __restrict__ W2, ushort_t* __restrict__ W2hi, ushort_t* __restrict__ W2lo,
    const float* __restrict__ W3, ushort_t* __restrict__ W3hi, ushort_t* __restrict__ W3lo) {
  if ((int)blockIdx.x < iblocks) {
    int i = blockIdx.x * 256 + threadIdx.x;
    if (i < MAXB) bucket_total[i] = 0;
  } else {
    int idx = ((int)blockIdx.x - iblocks) * 256 + threadIdx.x;
    constexpr int S1 = DIN * HID;        // 32768
    constexpr int S2 = S1 + HID * HID;   // 49152
    constexpr int S3 = S2 + HID * DOUT;  // 57344
    if (idx < S1) wprep_one(W1, W1hi, W1lo, DIN, HID, idx);
    else if (idx < S2) wprep_one(W2, W2hi, W2lo, HID, HID, idx - S1);
    else if (idx < S3) wprep_one(W3, W3hi, W3lo, HID, DOUT, idx - S2);
  }
}

// ---------- bin pass: per-block LDS histogram over buckets ----------
// One returning global atomic per (block,bucket) -> block's base within bucket.

__global__ __launch_bounds__(256) void bin_kernel(const int* __restrict__ dst, int e,
    int nbuckets, int* __restrict__ bucket_total, int* __restrict__ block_base) {
  __shared__ int h[MAXB];
  int tid = threadIdx.x;
  for (int i = tid; i < nbuckets; i += 256) h[i] = 0;
  __syncthreads();
  int base = blockIdx.x * EPB;
  int end = min(base + EPB, e);
  for (int i = base + tid; i < end; i += 256) atomicAdd(&h[dst[i] >> BSH], 1);
  __syncthreads();
  for (int i = tid; i < nbuckets; i += 256) {
    int v = h[i];
    if (v) block_base[(size_t)blockIdx.x * nbuckets + i] = atomicAdd(&bucket_total[i], v);
  }
}

// ---------- bucket scan: exclusive scan of bucket_total (+ sentinel) ----------

__global__ __launch_bounds__(256) void scan_buckets_kernel(const int* __restrict__ total,
    int* __restrict__ base, int nb) {
  __shared__ int sums[256];
  int t = threadIdx.x;
  int a[4];
  int ls = 0;
#pragma unroll
  for (int k = 0; k < 4; ++k) {
    int idx = t * 4 + k;
    a[k] = (idx < nb) ? total[idx] : 0;
    ls += a[k];
  }
  sums[t] = ls;
  __syncthreads();
  for (int off = 1; off < 256; off <<= 1) {
    int u = (t >= off) ? sums[t - off] : 0;
    __syncthreads();
    sums[t] += u;
    __syncthreads();
  }
  int run = sums[t] - ls;  // exclusive
#pragma unroll
  for (int k = 0; k < 4; ++k) {
    int idx = t * 4 + k;
    if (idx < nb) base[idx] = run;
    run += a[k];
  }
  if (t == 255) base[nb] = sums[255];  // sentinel = e
}

// ---------- split-bf16 MFMA GEMM (device fn) ----------
// 256 threads = 4 waves; 64 rows per block-id; wave w: rows +16w..+16w+15.
// acc = Ahi*Bhi + Alo*Bhi + Ahi*Blo (fp32 accum; lo*lo dropped, ~2^-18 rel).

template <int K, int F, bool SCALE>
__device__ inline void gemm_mfma_dev(const float* __restrict__ X,
    const ushort_t* __restrict__ Bhi, const ushort_t* __restrict__ Blo,
    const float* __restrict__ dinv, ushort_t* __restrict__ T, int n, int bid) {
  constexpr int NT = F / 16;   // n-tiles
  constexpr int KS = K / 32;   // k-steps
  int wave = threadIdx.x >> 6;
  int lane = threadIdx.x & 63;
  int q = lane >> 4;
  int m = lane & 15;
  int arow = bid * 64 + wave * 16 + m;
  bool valid = arow < n;
  const float* xrow = X + (size_t)arow * K;

  f32x4 acc[NT];
#pragma unroll
  for (int t = 0; t < NT; ++t) acc[t] = (f32x4){0.f, 0.f, 0.f, 0.f};

  for (int s = 0; s < KS; ++s) {
    float av[8];
    if (valid) {
      float4 u0 = *(const float4*)(xrow + s * 32 + q * 8);
      float4 u1 = *(const float4*)(xrow + s * 32 + q * 8 + 4);
      av[0] = u0.x; av[1] = u0.y; av[2] = u0.z; av[3] = u0.w;
      av[4] = u1.x; av[5] = u1.y; av[6] = u1.z; av[7] = u1.w;
    } else {
#pragma unroll
      for (int j = 0; j < 8; ++j) av[j] = 0.f;
    }
    bf16x8 ahi, alo;
#pragma unroll
    for (int j = 0; j < 8; ++j) {
      ushort_t h = f2bf(av[j]);
      ahi[j] = (short)h;
      alo[j] = (short)f2bf(av[j] - bf2f(h));
    }
#pragma unroll
    for (int t = 0; t < NT; ++t) {
      size_t boff = (((size_t)t * KS + s) * 64 + (size_t)lane) * 8;
      bf16x8 bh = *(const bf16x8*)(Bhi + boff);
      bf16x8 bl = *(const bf16x8*)(Blo + boff);
      acc[t] = __builtin_amdgcn_mfma_f32_16x16x32_bf16(ahi, bh, acc[t], 0, 0, 0);
      acc[t] = __builtin_amdgcn_mfma_f32_16x16x32_bf16(alo, bh, acc[t], 0, 0, 0);
      acc[t] = __builtin_amdgcn_mfma_f32_16x16x32_bf16(ahi, bl, acc[t], 0, 0, 0);
    }
  }

  int orow_base = bid * 64 + wave * 16 + q * 4;
#pragma unroll
  for (int r = 0; r < 4; ++r) {
    int orow = orow_base + r;
    if (orow >= n) continue;
    float sc = SCALE ? dinv[orow] : 1.0f;
    ushort_t* trow = T + (size_t)orow * F + m;
#pragma unroll
    for (int t = 0; t < NT; ++t) trow[t * 16] = f2bf(sc * acc[t][r]);
  }
}

// ---------- fused A2: [gemm1 unscaled | scatter into buckets] ----------
// scatter: LDS re-histogram gives rank within (block,bucket); position =
// bucket_base[b] + block_base[blk][b] + rank. Zero global atomics.

__global__ __launch_bounds__(256) void fusedA2_kernel(
    const float* __restrict__ X, const ushort_t* __restrict__ Bhi,
    const ushort_t* __restrict__ Blo, ushort_t* __restrict__ T, int n, int gblocks,
    const int* __restrict__ src, const int* __restrict__ dst,
    const int* __restrict__ bucket_base, const int* __restrict__ block_base,
    uint_t* __restrict__ binned, int e, int nbuckets) {
  if ((int)blockIdx.x < gblocks) {
    gemm_mfma_dev<DIN, HID, false>(X, Bhi, Blo, nullptr, T, n, blockIdx.x);
  } else {
    __shared__ int rkh[MAXB];
    __shared__ int cbase[MAXB];
    int tid = threadIdx.x;
    int blk = (int)blockIdx.x - gblocks;
    for (int i = tid; i < nbuckets; i += 256) {
      rkh[i] = 0;
      cbase[i] = bucket_base[i] + block_base[(size_t)blk * nbuckets + i];
    }
    __syncthreads();
    int base = blk * EPB;
    int end = min(base + EPB, e);
    for (int i = base + tid; i < end; i += 256) {
      int d = dst[i];
      int s = src[i];
      int b = d >> BSH;
      int r = atomicAdd(&rkh[b], 1);
      binned[cbase[b] + r] = ((uint_t)d << 16) | (uint_t)s;
    }
  }
}

// ---------- per-bucket CSR build: deg, dinv, row_start, col ----------
// Bucket = contiguous node range -> offsets are bucket-local; no global scan.

__global__ __launch_bounds__(256) void csr_kernel(const uint_t* __restrict__ binned,
    const int* __restrict__ bucket_base, int n, int* __restrict__ row_start,
    int* __restrict__ deg, float* __restrict__ dinv, int* __restrict__ col) {
  __shared__ int cnt[64];
  __shared__ int rk[64];
  __shared__ int rs[64];
  __shared__ int ebs[2];
  int tid = threadIdx.x;
  int b = blockIdx.x;
  int node0 = b << BSH;
  if (tid < 64) { cnt[tid] = 0; rk[tid] = 0; }
  if (tid == 0) { ebs[0] = bucket_base[b]; ebs[1] = bucket_base[b + 1]; }
  __syncthreads();
  int ebase = ebs[0];
  int esz = ebs[1] - ebase;
  for (int i = tid; i < esz; i += 256)
    atomicAdd(&cnt[(int)(binned[ebase + i] >> 16) - node0], 1);
  __syncthreads();
  if (tid < 64) {
    int v = cnt[tid];
    int inc = v;
#pragma unroll
    for (int off = 1; off < 64; off <<= 1) {
      int u = __shfl_up(inc, off, 64);
      if (tid >= off) inc += u;
    }
    rs[tid] = inc - v;  // exclusive within bucket
    int node = node0 + tid;
    if (node < n) {
      deg[node] = v + 1;                      // + self-loop
      dinv[node] = rsqrtf((float)(v + 1));
      row_start[node] = ebase + (inc - v);
    }
  }
  __syncthreads();
  for (int i = tid; i < esz; i += 256) {
    uint_t p = binned[ebase + i];
    int l = (int)(p >> 16) - node0;
    int r = atomicAdd(&rk[l], 1);
    col[ebase + rs[l] + r] = (int)(p & 0xFFFFu);
  }
}

// ---------- fused SpMM + GEMM (inner layers) ----------
// Phase 1: 4 waves x 8 nodes, dual-node MLP gather chains; h = relu(agg + b)
//          stored fp32 to LDS agg[32][132] (pad 132 -> phase-2 reads are a
//          free 2-way bank alias instead of 16-way conflict).
// Phase 2: 32x128 @ 128xFOUT MFMA. wave -> (mtile = w&1, tile-group = w>>1);
//          A from LDS (hi/lo split), B = wprep fragments (L2-resident 64KB),
//          out = dinv-scaled bf16 rows of Tout (ready for next SpMM, GD=false).
// GD=true (layer 1): input rows unscaled -> gather dinv[c] per edge.

template <int FOUT, bool GD>
__global__ __launch_bounds__(256) void spmm_gemm_kernel(
    const ushort_t* __restrict__ t, const int* __restrict__ row_start,
    const int* __restrict__ deg, const int* __restrict__ col,
    const float* __restrict__ dinv, const float* __restrict__ bias,
    const ushort_t* __restrict__ Bhi, const ushort_t* __restrict__ Blo,
    ushort_t* __restrict__ Tout, int n) {
  constexpr int FIN = 128;
  constexpr int NPB = 32;       // nodes per block
  constexpr int LDW = FIN + 4;  // LDS row stride (floats)
  __shared__ float agg[NPB][LDW];
  int wave = threadIdx.x >> 6;
  int lane = threadIdx.x & 63;
  int nb0 = (int)blockIdx.x * NPB;
  float bx = bias[2 * lane], by = bias[2 * lane + 1];

  // ---- phase 1: gather-aggregate ----
  for (int p = 0; p < 4; ++p) {
    int ln0 = wave * 8 + 2 * p;
    int n0 = nb0 + ln0;
    int n1 = n0 + 1;
    bool h0 = n0 < n, h1 = n1 < n;
    int rs0 = h0 ? row_start[n0] : 0, e0 = h0 ? deg[n0] - 1 : 0;
    int rs1 = h1 ? row_start[n1] : 0, e1 = h1 ? deg[n1] - 1 : 0;
    float di0 = h0 ? dinv[n0] : 0.f;
    float di1 = h1 ? dinv[n1] : 0.f;
    float ax0 = 0.f, ay0 = 0.f, ax1 = 0.f, ay1 = 0.f;
    if (h0) {
      uint_t s0 = ((const uint_t*)(t + (size_t)n0 * FIN))[lane];
      ax0 = bf2f((ushort_t)(s0 & 0xFFFF)); ay0 = bf2f((ushort_t)(s0 >> 16));
      if constexpr (GD) { ax0 *= di0; ay0 *= di0; }
    }
    if (h1) {
      uint_t s1 = ((const uint_t*)(t + (size_t)n1 * FIN))[lane];
      ax1 = bf2f((ushort_t)(s1 & 0xFFFF)); ay1 = bf2f((ushort_t)(s1 >> 16));
      if constexpr (GD) { ax1 *= di1; ay1 *= di1; }
    }
    int p0 = rs0, q0 = rs0 + e0;
    int p1 = rs1, q1 = rs1 + e1;
    while (p0 + 4 <= q0 && p1 + 4 <= q1) {
      int c[8];
      uint_t v[8];
      float dc[8];
#pragma unroll
      for (int j = 0; j < 4; ++j) { c[j] = col[p0 + j]; c[4 + j] = col[p1 + j]; }
#pragma unroll
      for (int j = 0; j < 8; ++j) {
        v[j] = ((const uint_t*)(t + (size_t)c[j] * FIN))[lane];
        if constexpr (GD) dc[j] = dinv[c[j]];
      }
#pragma unroll
      for (int j = 0; j < 4; ++j) {
        if constexpr (GD) {
          ax0 = fmaf(dc[j], bf2f((ushort_t)(v[j] & 0xFFFF)), ax0);
          ay0 = fmaf(dc[j], bf2f((ushort_t)(v[j] >> 16)), ay0);
          ax1 = fmaf(dc[4 + j], bf2f((ushort_t)(v[4 + j] & 0xFFFF)), ax1);
          ay1 = fmaf(dc[4 + j], bf2f((ushort_t)(v[4 + j] >> 16)), ay1);
        } else {
          ax0 += bf2f((ushort_t)(v[j] & 0xFFFF));
          ay0 += bf2f((ushort_t)(v[j] >> 16));
          ax1 += bf2f((ushort_t)(v[4 + j] & 0xFFFF));
          ay1 += bf2f((ushort_t)(v[4 + j] >> 16));
        }
      }
      p0 += 4; p1 += 4;
    }
    for (; p0 + 4 <= q0; p0 += 4) {
      int c[4]; uint_t v[4]; float dc[4];
#pragma unroll
      for (int j = 0; j < 4; ++j) c[j] = col[p0 + j];
#pragma unroll
      for (int j = 0; j < 4; ++j) {
        v[j] = ((const uint_t*)(t + (size_t)c[j] * FIN))[lane];
        if constexpr (GD) dc[j] = dinv[c[j]];
      }
#pragma unroll
      for (int j = 0; j < 4; ++j) {
        if constexpr (GD) {
          ax0 = fmaf(dc[j], bf2f((ushort_t)(v[j] & 0xFFFF)), ax0);
          ay0 = fmaf(dc[j], bf2f((ushort_t)(v[j] >> 16)), ay0);
        } else {
          ax0 += bf2f((ushort_t)(v[j] & 0xFFFF)); ay0 += bf2f((ushort_t)(v[j] >> 16));
        }
      }
    }
    for (; p0 < q0; ++p0) {
      int c = col[p0];
      uint_t v = ((const uint_t*)(t + (size_t)c * FIN))[lane];
      if constexpr (GD) {
        float d = dinv[c];
        ax0 = fmaf(d, bf2f((ushort_t)(v & 0xFFFF)), ax0);
        ay0 = fmaf(d, bf2f((ushort_t)(v >> 16)), ay0);
      } else {
        ax0 += bf2f((ushort_t)(v & 0xFFFF)); ay0 += bf2f((ushort_t)(v >> 16));
      }
    }
    for (; p1 + 4 <= q1; p1 += 4) {
      int c[4]; uint_t v[4]; float dc[4];
#pragma unroll
      for (int j = 0; j < 4; ++j) c[j] = col[p1 + j];
#pragma unroll
      for (int j = 0; j < 4; ++j) {
        v[j] = ((const uint_t*)(t + (size_t)c[j] * FIN))[lane];
        if constexpr (GD) dc[j] = dinv[c[j]];
      }
#pragma unroll
      for (int j = 0; j < 4; ++j) {
        if constexpr (GD) {
          ax1 = fmaf(dc[j], bf2f((ushort_t)(v[j] & 0xFFFF)), ax1);
          ay1 = fmaf(dc[j], bf2f((ushort_t)(v[j] >> 16)), ay1);
        } else {
          ax1 += bf2f((ushort_t)(v[j] & 0xFFFF)); ay1 += bf2f((ushort_t)(v[j] >> 16));
        }
      }
    }
    for (; p1 < q1; ++p1) {
      int c = col[p1];
      uint_t v = ((const uint_t*)(t + (size_t)c * FIN))[lane];
      if constexpr (GD) {
        float d = dinv[c];
        ax1 = fmaf(d, bf2f((ushort_t)(v & 0xFFFF)), ax1);
        ay1 = fmaf(d, bf2f((ushort_t)(v >> 16)), ay1);
      } else {
        ax1 += bf2f((ushort_t)(v & 0xFFFF)); ay1 += bf2f((ushort_t)(v >> 16));
      }
    }
    float2 o0, o1;
    o0.x = h0 ? fmaxf(fmaf(di0, ax0, bx), 0.f) : 0.f;
    o0.y = h0 ? fmaxf(fmaf(di0, ay0, by), 0.f) : 0.f;
    o1.x = h1 ? fmaxf(fmaf(di1, ax1, bx), 0.f) : 0.f;
    o1.y = h1 ? fmaxf(fmaf(di1, ay1, by), 0.f) : 0.f;
    *(float2*)&agg[ln0][2 * lane] = o0;
    *(float2*)&agg[ln0 + 1][2 * lane] = o1;
  }
  __syncthreads();

  // ---- phase 2: 32x128 @ 128xFOUT MFMA ----
  constexpr int NT = FOUT / 16;
  constexpr int KS = FIN / 32;
  constexpr int NTW = NT / 2;   // tiles per wave (2 waves per tile-group)
  int mt = wave & 1;
  int g = wave >> 1;
  int q = lane >> 4, m = lane & 15;
  f32x4 acc[NTW];
#pragma unroll
  for (int tt = 0; tt < NTW; ++tt) acc[tt] = (f32x4){0.f, 0.f, 0.f, 0.f};
  const float* arow = &agg[mt * 16 + m][0];
#pragma unroll
  for (int s = 0; s < KS; ++s) {
    float4 u0 = *(const float4*)(arow + s * 32 + q * 8);
    float4 u1 = *(const float4*)(arow + s * 32 + q * 8 + 4);
    float av[8];
    av[0] = u0.x; av[1] = u0.y; av[2] = u0.z; av[3] = u0.w;
    av[4] = u1.x; av[5] = u1.y; av[6] = u1.z; av[7] = u1.w;
    bf16x8 ahi, alo;
#pragma unroll
    for (int j = 0; j < 8; ++j) {
      ushort_t h = f2bf(av[j]);
      ahi[j] = (short)h;
      alo[j] = (short)f2bf(av[j] - bf2f(h));
    }
#pragma unroll
    for (int tt = 0; tt < NTW; ++tt) {
      int tg = g * NTW + tt;
      size_t boff = (((size_t)tg * KS + s) * 64 + (size_t)lane) * 8;
      bf16x8 bh = *(const bf16x8*)(Bhi + boff);
      bf16x8 bl = *(const bf16x8*)(Blo + boff);
      acc[tt] = __builtin_amdgcn_mfma_f32_16x16x32_bf16(ahi, bh, acc[tt], 0, 0, 0);
      acc[tt] = __builtin_amdgcn_mfma_f32_16x16x32_bf16(alo, bh, acc[tt], 0, 0, 0);
      acc[tt] = __builtin_amdgcn_mfma_f32_16x16x32_bf16(ahi, bl, acc[tt], 0, 0, 0);
    }
  }
  int orow_base = nb0 + mt * 16 + q * 4;
#pragma unroll
  for (int r = 0; r < 4; ++r) {
    int orow = orow_base + r;
    if (orow >= n) continue;
    float sc = dinv[orow];
    ushort_t* trow = Tout + (size_t)orow * FOUT + m;
#pragma unroll
    for (int tt = 0; tt < NTW; ++tt) trow[(g * NTW + tt) * 16] = f2bf(sc * acc[tt][r]);
  }
}

// ---------- CSR SpMM (final layer): out = dinv*(T'[d] + sum T'[c]) + b ----------
// T' rows bf16 pre-scaled. TWO destination nodes per wave.

template <int F, bool RELU, bool GD>
__global__ __launch_bounds__(256) void spmm_kernel(const ushort_t* __restrict__ t,
    const int* __restrict__ row_start, const int* __restrict__ deg,
    const int* __restrict__ col, const float* __restrict__ dinv,
    const float* __restrict__ bias, float* __restrict__ out, int n) {
  int gw = (int)((blockIdx.x * 256u + threadIdx.x) >> 6);
  int lane = threadIdx.x & 63;
  int n0 = gw * 2;
  int n1 = n0 + 1;
  if (n0 >= n) return;
  bool h1 = (n1 < n);
  int rs0 = row_start[n0], e0 = deg[n0] - 1;
  int rs1 = h1 ? row_start[n1] : 0, e1 = h1 ? (deg[n1] - 1) : 0;
  float di0 = dinv[n0];
  float di1 = h1 ? dinv[n1] : 0.f;

  if constexpr (F == 128) {
    uint_t s0 = ((const uint_t*)(t + (size_t)n0 * F))[lane];
    float ax0 = bf2f((ushort_t)(s0 & 0xFFFF)), ay0 = bf2f((ushort_t)(s0 >> 16));
    float ax1 = 0.f, ay1 = 0.f;
    if (h1) {
      uint_t s1 = ((const uint_t*)(t + (size_t)n1 * F))[lane];
      ax1 = bf2f((ushort_t)(s1 & 0xFFFF)); ay1 = bf2f((ushort_t)(s1 >> 16));
    }
    int p0 = rs0, q0 = rs0 + e0;
    int p1 = rs1, q1 = rs1 + e1;
    while (p0 + 4 <= q0 && p1 + 4 <= q1) {
      int c[8];
      uint_t v[8];
#pragma unroll
      for (int j = 0; j < 4; ++j) { c[j] = col[p0 + j]; c[4 + j] = col[p1 + j]; }
#pragma unroll
      for (int j = 0; j < 8; ++j) v[j] = ((const uint_t*)(t + (size_t)c[j] * F))[lane];
#pragma unroll
      for (int j = 0; j < 4; ++j) {
        ax0 += bf2f((ushort_t)(v[j] & 0xFFFF));
        ay0 += bf2f((ushort_t)(v[j] >> 16));
        ax1 += bf2f((ushort_t)(v[4 + j] & 0xFFFF));
        ay1 += bf2f((ushort_t)(v[4 + j] >> 16));
      }
      p0 += 4; p1 += 4;
    }
    for (; p0 + 4 <= q0; p0 += 4) {
      int c[4]; uint_t v[4];
#pragma unroll
      for (int j = 0; j < 4; ++j) c[j] = col[p0 + j];
#pragma unroll
      for (int j = 0; j < 4; ++j) v[j] = ((const uint_t*)(t + (size_t)c[j] * F))[lane];
#pragma unroll
      for (int j = 0; j < 4; ++j) {
        ax0 += bf2f((ushort_t)(v[j] & 0xFFFF)); ay0 += bf2f((ushort_t)(v[j] >> 16));
      }
    }
    for (; p0 < q0; ++p0) {
      uint_t v = ((const uint_t*)(t + (size_t)col[p0] * F))[lane];
      ax0 += bf2f((ushort_t)(v & 0xFFFF)); ay0 += bf2f((ushort_t)(v >> 16));
    }
    for (; p1 + 4 <= q1; p1 += 4) {
      int c[4]; uint_t v[4];
#pragma unroll
      for (int j = 0; j < 4; ++j) c[j] = col[p1 + j];
#pragma unroll
      for (int j = 0; j < 4; ++j) v[j] = ((const uint_t*)(t + (size_t)c[j] * F))[lane];
#pragma unroll
      for (int j = 0; j < 4; ++j) {
        ax1 += bf2f((ushort_t)(v[j] & 0xFFFF)); ay1 += bf2f((ushort_t)(v[j] >> 16));
      }
    }
    for (; p1 < q1; ++p1) {
      uint_t v = ((const uint_t*)(t + (size_t)col[p1] * F))[lane];
      ax1 += bf2f((ushort_t)(v & 0xFFFF)); ay1 += bf2f((ushort_t)(v >> 16));
    }
    float bx = bias[2 * lane], by = bias[2 * lane + 1];
    ax0 = fmaf(di0, ax0, bx); ay0 = fmaf(di0, ay0, by);
    if constexpr (RELU) { ax0 = fmaxf(ax0, 0.f); ay0 = fmaxf(ay0, 0.f); }
    float2 o0; o0.x = ax0; o0.y = ay0;
    ((float2*)(out + (size_t)n0 * F))[lane] = o0;
    if (h1) {
      ax1 = fmaf(di1, ax1, bx); ay1 = fmaf(di1, ay1, by);
      if constexpr (RELU) { ax1 = fmaxf(ax1, 0.f); ay1 = fmaxf(ay1, 0.f); }
      float2 o1; o1.x = ax1; o1.y = ay1;
      ((float2*)(out + (size_t)n1 * F))[lane] = o1;
    }
  } else {  // F == 64: one bf16 per lane
    float a0 = bf2f(t[(size_t)n0 * F + lane]);
    float a1 = h1 ? bf2f(t[(size_t)n1 * F + lane]) : 0.f;
    int p0 = rs0, q0 = rs0 + e0;
    int p1 = rs1, q1 = rs1 + e1;
    while (p0 + 4 <= q0 && p1 + 4 <= q1) {
      int c[8];
      ushort_t v[8];
#pragma unroll
      for (int j = 0; j < 4; ++j) { c[j] = col[p0 + j]; c[4 + j] = col[p1 + j]; }
#pragma unroll
      for (int j = 0; j < 8; ++j) v[j] = t[(size_t)c[j] * F + lane];
#pragma unroll
      for (int j = 0; j < 4; ++j) { a0 += bf2f(v[j]); a1 += bf2f(v[4 + j]); }
      p0 += 4; p1 += 4;
    }
    for (; p0 + 4 <= q0; p0 += 4) {
      int c[4]; ushort_t v[4];
#pragma unroll
      for (int j = 0; j < 4; ++j) c[j] = col[p0 + j];
#pragma unroll
      for (int j = 0; j < 4; ++j) v[j] = t[(size_t)c[j] * F + lane];
#pragma unroll
      for (int j = 0; j < 4; ++j) a0 += bf2f(v[j]);
    }
    for (; p0 < q0; ++p0) a0 += bf2f(t[(size_t)col[p0] * F + lane]);
    for (; p1 + 4 <= q1; p1 += 4) {
      int c[4]; ushort_t v[4];
#pragma unroll
      for (int j = 0; j < 4; ++j) c[j] = col[p1 + j];
#pragma unroll
      for (int j = 0; j < 4; ++j) v[j] = t[(size_t)c[j] * F + lane];
#pragma unroll
      for (int j = 0; j < 4; ++j) a1 += bf2f(v[j]);
    }
    for (; p1 < q1; ++p1) a1 += bf2f(t[(size_t)col[p1] * F + lane]);
    float b = bias[lane];
    a0 = fmaf(di0, a0, b);
    if constexpr (RELU) a0 = fmaxf(a0, 0.f);
    out[(size_t)n0 * F + lane] = a0;
    if (h1) {
      a1 = fmaf(di1, a1, b);
      if constexpr (RELU) a1 = fmaxf(a1, 0.f);
      out[(size_t)n1 * F + lane] = a1;
    }
  }
}

// ---------- launch ----------

extern "C" void kernel_launch(void* const* d_in, const int* in_sizes, int n_in,
                              void* d_out, int out_size, void* d_ws, size_t ws_size,
                              hipStream_t stream) {
  const float* x  = (const float*)d_in[0];
  const float* W1 = (const float*)d_in[1];
  const float* b1 = (const float*)d_in[2];
  const float* W2 = (const float*)d_in[3];
  const float* b2 = (const float*)d_in[4];
  const float* W3 = (const float*)d_in[5];
  const float* b3 = (const float*)d_in[6];
  const int* ei   = (const int*)d_in[7];  // harness delivers integers as int32

  int n = in_sizes[0] / DIN;
  int e = in_sizes[7] / 2;
  const int* src = ei;
  const int* dst = ei + e;

  char* ws = (char*)d_ws;
  size_t off = 0;
  auto alloc = [&](size_t bytes) -> void* {
    off = (off + 255) & ~(size_t)255;
    void* p = ws + off;
    off += bytes;
    return p;
  };
  int nbuckets = (n + 63) >> BSH;          // <= MAXB for n <= 65536
  int nbin = (e + EPB - 1) / EPB;

  int*      bucket_total = (int*)alloc((size_t)MAXB * 4);
  int*      bucket_base  = (int*)alloc((size_t)(MAXB + 1) * 4);
  int*      block_base   = (int*)alloc((size_t)nbin * nbuckets * 4);
  uint_t*   binned       = (uint_t*)alloc((size_t)e * 4);
  int*      deg          = (int*)alloc((size_t)n * 4);
  float*    dinv         = (float*)alloc((size_t)n * 4);
  int*      row_start    = (int*)alloc((size_t)n * 4);
  int*      col          = (int*)alloc((size_t)e * 4);
  ushort_t* Ta           = (ushort_t*)alloc((size_t)n * HID * 2);  // bf16 rows
  ushort_t* Tb           = (ushort_t*)alloc((size_t)n * HID * 2);  // bf16 rows
  ushort_t* W1hi         = (ushort_t*)alloc((size_t)DIN * HID * 2);
  ushort_t* W1lo         = (ushort_t*)alloc((size_t)DIN * HID * 2);
  ushort_t* W2hi         = (ushort_t*)alloc((size_t)HID * HID * 2);
  ushort_t* W2lo         = (ushort_t*)alloc((size_t)HID * HID * 2);
  ushort_t* W3hi         = (ushort_t*)alloc((size_t)HID * DOUT * 2);
  ushort_t* W3lo         = (ushort_t*)alloc((size_t)HID * DOUT * 2);
  (void)ws_size;

  int gemm_blocks = (n + 63) / 64;
  int sg_blocks = (n + 31) / 32;            // fused spmm_gemm: 32 nodes/block
  int nwaves = (n + 1) / 2;                 // 2 nodes per wave (final spmm)
  int spmm_blocks = (nwaves + 3) / 4;       // 4 waves per block
  constexpr int WPREP_TOTAL = DIN * HID + HID * HID + HID * DOUT;  // 57344
  int wblocks = (WPREP_TOTAL + 255) / 256;  // 224
  int iblocks = MAXB / 256;                 // 4

  initprep_kernel<<<iblocks + wblocks, 256, 0, stream>>>(
      bucket_total, iblocks,
      W1, W1hi, W1lo, W2, W2hi, W2lo, W3, W3hi, W3lo);
  bin_kernel<<<nbin, 256, 0, stream>>>(dst, e, nbuckets, bucket_total, block_base);
  scan_buckets_kernel<<<1, 256, 0, stream>>>(bucket_total, bucket_base, nbuckets);
  fusedA2_kernel<<<gemm_blocks + nbin, 256, 0, stream>>>(
      x, W1hi, W1lo, Ta, n, gemm_blocks,
      src, dst, bucket_base, block_base, binned, e, nbuckets);
  csr_kernel<<<nbuckets, 256, 0, stream>>>(binned, bucket_base, n, row_start, deg, dinv, col);

  // layer 1 agg + layer 2 GEMM (fused): Ta (unscaled, GD) -> Tb (scaled bf16)
  spmm_gemm_kernel<HID, true><<<sg_blocks, 256, 0, stream>>>(
      Ta, row_start, deg, col, dinv, b1, W2hi, W2lo, Tb, n);
  // layer 2 agg + layer 3 GEMM (fused): Tb -> Ta (n x 64, scaled bf16)
  spmm_gemm_kernel<DOUT, false><<<sg_blocks, 256, 0, stream>>>(
      Tb, row_start, deg, col, dinv, b2, W3hi, W3lo, Ta, n);
  // layer 3 agg (final): Ta -> out (fp32) + b3
  spmm_kernel<DOUT, false, false><<<spmm_blocks, 256, 0, stream>>>(
      Ta, row_start, deg, col, dinv, b3, (float*)d_out, n);
}

// Round 4
// 348.088 us; speedup vs baseline: 1.0303x; 1.0303x over previous
//
#include <hip/hip_runtime.h>

// GCN 3-layer: N=50000, E=1.6M, D_IN=256, H=128, D_OUT=64, fp32 in/out.
// R12: bucketed counting sort killed the global-atomic wall (~17G/s ceiling).
// R13: fused SpMM+GEMM at 32 nodes/block REGRESSED (97us vs 58+15): grid
//   dropped to 1563 blocks = 0.76x device wave slots -> occupancy 39%,
//   gather BW fell proportionally (random gather is latency x parallelism
//   limited; BW ~ resident waves).
// R14: keep the fusion, restore parallelism: 8 nodes/block (6250 blocks,
//   3x oversubscription -- the proven 58us standalone-spmm structure),
//   MFMA on a zero-padded 16-row tile (rows 8-15 zeroed; phase 2 is ~3% of
//   block time, wasting half of it is cheap). One barrier over 4 waves.
// Pipeline: initprep -> bin -> scan -> fusedA2[gemm1|scatter] -> csr ->
//   spmm_gemm<128,GD> -> spmm_gemm<64> -> spmm<64> = 7 launches.
// Requires n <= 65536 (16-bit packing; harness n = 50000).

constexpr int DIN = 256;
constexpr int HID = 128;
constexpr int DOUT = 64;
constexpr int MAXB = 1024;   // max buckets (n <= 65536)
constexpr int BSH = 6;       // 64 nodes per bucket
constexpr int EPB = 8192;    // edges per bin/scatter block

typedef unsigned short ushort_t;
typedef unsigned int uint_t;
typedef __attribute__((ext_vector_type(8))) short bf16x8;
typedef __attribute__((ext_vector_type(4))) float f32x4;

__device__ inline ushort_t f2bf(float f) {
  uint_t u = __float_as_uint(f);
  u += 0x7FFF + ((u >> 16) & 1);  // RNE
  return (ushort_t)(u >> 16);
}
__device__ inline float bf2f(ushort_t b) {
  return __uint_as_float(((uint_t)b) << 16);
}

// ---------- weight prep (device fn): W[K][F] fp32 -> fragment bf16 hi/lo ----------
// Layout: Bp[t = n/16][s = k/32][lane = (k/8 % 4)*16 + n%16][j = k%8]

__device__ inline void wprep_one(const float* __restrict__ W, ushort_t* __restrict__ Bhi,
                                 ushort_t* __restrict__ Blo, int K, int F, int i) {
  int k = i / F, nn = i % F;
  int t = nn >> 4, s = k >> 5, q = (k >> 3) & 3, j = k & 7;
  int lane = q * 16 + (nn & 15);
  int KS = K >> 5;
  size_t idx = (((size_t)t * KS + s) * 64 + (size_t)lane) * 8 + j;
  float w = W[i];
  ushort_t h = f2bf(w);
  float r = w - bf2f(h);
  Bhi[idx] = h;
  Blo[idx] = f2bf(r);
}

// ---------- init: zero bucket_total + wprep x3 ----------

__global__ __launch_bounds__(256) void initprep_kernel(
    int* __restrict__ bucket_total, int iblocks,
    const float* __restrict__ W1, ushort_t* __restrict__ W1hi, ushort_t* __restrict__ W1lo,
    const float* __restrict__ W2, ushort_t* __restrict__ W2hi, ushort_t* __restrict__ W2lo,
    const float* __restrict__ W3, ushort_t* __restrict__ W3hi, ushort_t* __restrict__ W3lo) {
  if ((int)blockIdx.x < iblocks) {
    int i = blockIdx.x * 256 + threadIdx.x;
    if (i < MAXB) bucket_total[i] = 0;
  } else {
    int idx = ((int)blockIdx.x - iblocks) * 256 + threadIdx.x;
    constexpr int S1 = DIN * HID;        // 32768
    constexpr int S2 = S1 + HID * HID;   // 49152
    constexpr int S3 = S2 + HID * DOUT;  // 57344
    if (idx < S1) wprep_one(W1, W1hi, W1lo, DIN, HID, idx);
    else if (idx < S2) wprep_one(W2, W2hi, W2lo, HID, HID, idx - S1);
    else if (idx < S3) wprep_one(W3, W3hi, W3lo, HID, DOUT, idx - S2);
  }
}

// ---------- bin pass: per-block LDS histogram over buckets ----------
// One returning global atomic per (block,bucket) -> block's base within bucket.

__global__ __launch_bounds__(256) void bin_kernel(const int* __restrict__ dst, int e,
    int nbuckets, int* __restrict__ bucket_total, int* __restrict__ block_base) {
  __shared__ int h[MAXB];
  int tid = threadIdx.x;
  for (int i = tid; i < nbuckets; i += 256) h[i] = 0;
  __syncthreads();
  int base = blockIdx.x * EPB;
  int end = min(base + EPB, e);
  for (int i = base + tid; i < end; i += 256) atomicAdd(&h[dst[i] >> BSH], 1);
  __syncthreads();
  for (int i = tid; i < nbuckets; i += 256) {
    int v = h[i];
    if (v) block_base[(size_t)blockIdx.x * nbuckets + i] = atomicAdd(&bucket_total[i], v);
  }
}

// ---------- bucket scan: exclusive scan of bucket_total (+ sentinel) ----------

__global__ __launch_bounds__(256) void scan_buckets_kernel(const int* __restrict__ total,
    int* __restrict__ base, int nb) {
  __shared__ int sums[256];
  int t = threadIdx.x;
  int a[4];
  int ls = 0;
#pragma unroll
  for (int k = 0; k < 4; ++k) {
    int idx = t * 4 + k;
    a[k] = (idx < nb) ? total[idx] : 0;
    ls += a[k];
  }
  sums[t] = ls;
  __syncthreads();
  for (int off = 1; off < 256; off <<= 1) {
    int u = (t >= off) ? sums[t - off] : 0;
    __syncthreads();
    sums[t] += u;
    __syncthreads();
  }
  int run = sums[t] - ls;  // exclusive
#pragma unroll
  for (int k = 0; k < 4; ++k) {
    int idx = t * 4 + k;
    if (idx < nb) base[idx] = run;
    run += a[k];
  }
  if (t == 255) base[nb] = sums[255];  // sentinel = e
}

// ---------- split-bf16 MFMA GEMM (device fn) ----------
// 256 threads = 4 waves; 64 rows per block-id; wave w: rows +16w..+16w+15.
// acc = Ahi*Bhi + Alo*Bhi + Ahi*Blo (fp32 accum; lo*lo dropped, ~2^-18 rel).

template <int K, int F, bool SCALE>
__device__ inline void gemm_mfma_dev(const float* __restrict__ X,
    const ushort_t* __restrict__ Bhi, const ushort_t* __restrict__ Blo,
    const float* __restrict__ dinv, ushort_t* __restrict__ T, int n, int bid) {
  constexpr int NT = F / 16;   // n-tiles
  constexpr int KS = K / 32;   // k-steps
  int wave = threadIdx.x >> 6;
  int lane = threadIdx.x & 63;
  int q = lane >> 4;
  int m = lane & 15;
  int arow = bid * 64 + wave * 16 + m;
  bool valid = arow < n;
  const float* xrow = X + (size_t)arow * K;

  f32x4 acc[NT];
#pragma unroll
  for (int t = 0; t < NT; ++t) acc[t] = (f32x4){0.f, 0.f, 0.f, 0.f};

  for (int s = 0; s < KS; ++s) {
    float av[8];
    if (valid) {
      float4 u0 = *(const float4*)(xrow + s * 32 + q * 8);
      float4 u1 = *(const float4*)(xrow + s * 32 + q * 8 + 4);
      av[0] = u0.x; av[1] = u0.y; av[2] = u0.z; av[3] = u0.w;
      av[4] = u1.x; av[5] = u1.y; av[6] = u1.z; av[7] = u1.w;
    } else {
#pragma unroll
      for (int j = 0; j < 8; ++j) av[j] = 0.f;
    }
    bf16x8 ahi, alo;
#pragma unroll
    for (int j = 0; j < 8; ++j) {
      ushort_t h = f2bf(av[j]);
      ahi[j] = (short)h;
      alo[j] = (short)f2bf(av[j] - bf2f(h));
    }
#pragma unroll
    for (int t = 0; t < NT; ++t) {
      size_t boff = (((size_t)t * KS + s) * 64 + (size_t)lane) * 8;
      bf16x8 bh = *(const bf16x8*)(Bhi + boff);
      bf16x8 bl = *(const bf16x8*)(Blo + boff);
      acc[t] = __builtin_amdgcn_mfma_f32_16x16x32_bf16(ahi, bh, acc[t], 0, 0, 0);
      acc[t] = __builtin_amdgcn_mfma_f32_16x16x32_bf16(alo, bh, acc[t], 0, 0, 0);
      acc[t] = __builtin_amdgcn_mfma_f32_16x16x32_bf16(ahi, bl, acc[t], 0, 0, 0);
    }
  }

  int orow_base = bid * 64 + wave * 16 + q * 4;
#pragma unroll
  for (int r = 0; r < 4; ++r) {
    int orow = orow_base + r;
    if (orow >= n) continue;
    float sc = SCALE ? dinv[orow] : 1.0f;
    ushort_t* trow = T + (size_t)orow * F + m;
#pragma unroll
    for (int t = 0; t < NT; ++t) trow[t * 16] = f2bf(sc * acc[t][r]);
  }
}

// ---------- fused A2: [gemm1 unscaled | scatter into buckets] ----------
// scatter: LDS re-histogram gives rank within (block,bucket); position =
// bucket_base[b] + block_base[blk][b] + rank. Zero global atomics.

__global__ __launch_bounds__(256) void fusedA2_kernel(
    const float* __restrict__ X, const ushort_t* __restrict__ Bhi,
    const ushort_t* __restrict__ Blo, ushort_t* __restrict__ T, int n, int gblocks,
    const int* __restrict__ src, const int* __restrict__ dst,
    const int* __restrict__ bucket_base, const int* __restrict__ block_base,
    uint_t* __restrict__ binned, int e, int nbuckets) {
  if ((int)blockIdx.x < gblocks) {
    gemm_mfma_dev<DIN, HID, false>(X, Bhi, Blo, nullptr, T, n, blockIdx.x);
  } else {
    __shared__ int rkh[MAXB];
    __shared__ int cbase[MAXB];
    int tid = threadIdx.x;
    int blk = (int)blockIdx.x - gblocks;
    for (int i = tid; i < nbuckets; i += 256) {
      rkh[i] = 0;
      cbase[i] = bucket_base[i] + block_base[(size_t)blk * nbuckets + i];
    }
    __syncthreads();
    int base = blk * EPB;
    int end = min(base + EPB, e);
    for (int i = base + tid; i < end; i += 256) {
      int d = dst[i];
      int s = src[i];
      int b = d >> BSH;
      int r = atomicAdd(&rkh[b], 1);
      binned[cbase[b] + r] = ((uint_t)d << 16) | (uint_t)s;
    }
  }
}

// ---------- per-bucket CSR build: deg, dinv, row_start, col ----------
// Bucket = contiguous node range -> offsets are bucket-local; no global scan.

__global__ __launch_bounds__(256) void csr_kernel(const uint_t* __restrict__ binned,
    const int* __restrict__ bucket_base, int n, int* __restrict__ row_start,
    int* __restrict__ deg, float* __restrict__ dinv, int* __restrict__ col) {
  __shared__ int cnt[64];
  __shared__ int rk[64];
  __shared__ int rs[64];
  __shared__ int ebs[2];
  int tid = threadIdx.x;
  int b = blockIdx.x;
  int node0 = b << BSH;
  if (tid < 64) { cnt[tid] = 0; rk[tid] = 0; }
  if (tid == 0) { ebs[0] = bucket_base[b]; ebs[1] = bucket_base[b + 1]; }
  __syncthreads();
  int ebase = ebs[0];
  int esz = ebs[1] - ebase;
  for (int i = tid; i < esz; i += 256)
    atomicAdd(&cnt[(int)(binned[ebase + i] >> 16) - node0], 1);
  __syncthreads();
  if (tid < 64) {
    int v = cnt[tid];
    int inc = v;
#pragma unroll
    for (int off = 1; off < 64; off <<= 1) {
      int u = __shfl_up(inc, off, 64);
      if (tid >= off) inc += u;
    }
    rs[tid] = inc - v;  // exclusive within bucket
    int node = node0 + tid;
    if (node < n) {
      deg[node] = v + 1;                      // + self-loop
      dinv[node] = rsqrtf((float)(v + 1));
      row_start[node] = ebase + (inc - v);
    }
  }
  __syncthreads();
  for (int i = tid; i < esz; i += 256) {
    uint_t p = binned[ebase + i];
    int l = (int)(p >> 16) - node0;
    int r = atomicAdd(&rk[l], 1);
    col[ebase + rs[l] + r] = (int)(p & 0xFFFFu);
  }
}

// ---------- fused SpMM + GEMM (inner layers), 8 nodes/block ----------
// Phase 1: 4 waves x 1 dual-node chain each (EXACT standalone-spmm structure:
//          6250 blocks, 25K waves, 3x oversubscription -> gather BW restored).
//          h = relu(dinv*agg + b) stored fp32 to LDS agg[16][132]; rows 8-15
//          zeroed (pad 132 -> phase-2 reads are a free 2-way bank alias).
// Phase 2: 16(rows, 8 valid)x128 @ 128xFOUT MFMA; 4 waves x NT/4 tiles.
//          B = wprep fragments (L2-resident), out = dinv-scaled bf16 Tout.
// GD=true (layer 1): input rows unscaled -> gather dinv[c] per edge.

template <int FOUT, bool GD>
__global__ __launch_bounds__(256) void spmm_gemm_kernel(
    const ushort_t* __restrict__ t, const int* __restrict__ row_start,
    const int* __restrict__ deg, const int* __restrict__ col,
    const float* __restrict__ dinv, const float* __restrict__ bias,
    const ushort_t* __restrict__ Bhi, const ushort_t* __restrict__ Blo,
    ushort_t* __restrict__ Tout, int n) {
  constexpr int FIN = 128;
  constexpr int NPB = 8;        // nodes per block
  constexpr int LDW = FIN + 4;  // LDS row stride (floats)
  __shared__ float agg[16][LDW];
  int wave = threadIdx.x >> 6;
  int lane = threadIdx.x & 63;
  int tid = threadIdx.x;
  int nb0 = (int)blockIdx.x * NPB;

  // zero pad rows 8..15 (contiguous) -- disjoint from phase-1 writes
  {
    float* z = &agg[8][0];
    for (int i = tid; i < 8 * LDW; i += 256) z[i] = 0.f;
  }

  // ---- phase 1: gather-aggregate (1 dual-node chain per wave) ----
  {
    int ln0 = wave * 2;
    int n0 = nb0 + ln0;
    int n1 = n0 + 1;
    bool h0 = n0 < n, h1 = n1 < n;
    int rs0 = h0 ? row_start[n0] : 0, e0 = h0 ? deg[n0] - 1 : 0;
    int rs1 = h1 ? row_start[n1] : 0, e1 = h1 ? deg[n1] - 1 : 0;
    float di0 = h0 ? dinv[n0] : 0.f;
    float di1 = h1 ? dinv[n1] : 0.f;
    float bx = bias[2 * lane], by = bias[2 * lane + 1];
    float ax0 = 0.f, ay0 = 0.f, ax1 = 0.f, ay1 = 0.f;
    if (h0) {
      uint_t s0 = ((const uint_t*)(t + (size_t)n0 * FIN))[lane];
      ax0 = bf2f((ushort_t)(s0 & 0xFFFF)); ay0 = bf2f((ushort_t)(s0 >> 16));
      if constexpr (GD) { ax0 *= di0; ay0 *= di0; }
    }
    if (h1) {
      uint_t s1 = ((const uint_t*)(t + (size_t)n1 * FIN))[lane];
      ax1 = bf2f((ushort_t)(s1 & 0xFFFF)); ay1 = bf2f((ushort_t)(s1 >> 16));
      if constexpr (GD) { ax1 *= di1; ay1 *= di1; }
    }
    int p0 = rs0, q0 = rs0 + e0;
    int p1 = rs1, q1 = rs1 + e1;
    while (p0 + 4 <= q0 && p1 + 4 <= q1) {
      int c[8];
      uint_t v[8];
      float dc[8];
#pragma unroll
      for (int j = 0; j < 4; ++j) { c[j] = col[p0 + j]; c[4 + j] = col[p1 + j]; }
#pragma unroll
      for (int j = 0; j < 8; ++j) {
        v[j] = ((const uint_t*)(t + (size_t)c[j] * FIN))[lane];
        if constexpr (GD) dc[j] = dinv[c[j]];
      }
#pragma unroll
      for (int j = 0; j < 4; ++j) {
        if constexpr (GD) {
          ax0 = fmaf(dc[j], bf2f((ushort_t)(v[j] & 0xFFFF)), ax0);
          ay0 = fmaf(dc[j], bf2f((ushort_t)(v[j] >> 16)), ay0);
          ax1 = fmaf(dc[4 + j], bf2f((ushort_t)(v[4 + j] & 0xFFFF)), ax1);
          ay1 = fmaf(dc[4 + j], bf2f((ushort_t)(v[4 + j] >> 16)), ay1);
        } else {
          ax0 += bf2f((ushort_t)(v[j] & 0xFFFF));
          ay0 += bf2f((ushort_t)(v[j] >> 16));
          ax1 += bf2f((ushort_t)(v[4 + j] & 0xFFFF));
          ay1 += bf2f((ushort_t)(v[4 + j] >> 16));
        }
      }
      p0 += 4; p1 += 4;
    }
    for (; p0 + 4 <= q0; p0 += 4) {
      int c[4]; uint_t v[4]; float dc[4];
#pragma unroll
      for (int j = 0; j < 4; ++j) c[j] = col[p0 + j];
#pragma unroll
      for (int j = 0; j < 4; ++j) {
        v[j] = ((const uint_t*)(t + (size_t)c[j] * FIN))[lane];
        if constexpr (GD) dc[j] = dinv[c[j]];
      }
#pragma unroll
      for (int j = 0; j < 4; ++j) {
        if constexpr (GD) {
          ax0 = fmaf(dc[j], bf2f((ushort_t)(v[j] & 0xFFFF)), ax0);
          ay0 = fmaf(dc[j], bf2f((ushort_t)(v[j] >> 16)), ay0);
        } else {
          ax0 += bf2f((ushort_t)(v[j] & 0xFFFF)); ay0 += bf2f((ushort_t)(v[j] >> 16));
        }
      }
    }
    for (; p0 < q0; ++p0) {
      int c = col[p0];
      uint_t v = ((const uint_t*)(t + (size_t)c * FIN))[lane];
      if constexpr (GD) {
        float d = dinv[c];
        ax0 = fmaf(d, bf2f((ushort_t)(v & 0xFFFF)), ax0);
        ay0 = fmaf(d, bf2f((ushort_t)(v >> 16)), ay0);
      } else {
        ax0 += bf2f((ushort_t)(v & 0xFFFF)); ay0 += bf2f((ushort_t)(v >> 16));
      }
    }
    for (; p1 + 4 <= q1; p1 += 4) {
      int c[4]; uint_t v[4]; float dc[4];
#pragma unroll
      for (int j = 0; j < 4; ++j) c[j] = col[p1 + j];
#pragma unroll
      for (int j = 0; j < 4; ++j) {
        v[j] = ((const uint_t*)(t + (size_t)c[j] * FIN))[lane];
        if constexpr (GD) dc[j] = dinv[c[j]];
      }
#pragma unroll
      for (int j = 0; j < 4; ++j) {
        if constexpr (GD) {
          ax1 = fmaf(dc[j], bf2f((ushort_t)(v[j] & 0xFFFF)), ax1);
          ay1 = fmaf(dc[j], bf2f((ushort_t)(v[j] >> 16)), ay1);
        } else {
          ax1 += bf2f((ushort_t)(v[j] & 0xFFFF)); ay1 += bf2f((ushort_t)(v[j] >> 16));
        }
      }
    }
    for (; p1 < q1; ++p1) {
      int c = col[p1];
      uint_t v = ((const uint_t*)(t + (size_t)c * FIN))[lane];
      if constexpr (GD) {
        float d = dinv[c];
        ax1 = fmaf(d, bf2f((ushort_t)(v & 0xFFFF)), ax1);
        ay1 = fmaf(d, bf2f((ushort_t)(v >> 16)), ay1);
      } else {
        ax1 += bf2f((ushort_t)(v & 0xFFFF)); ay1 += bf2f((ushort_t)(v >> 16));
      }
    }
    float2 o0, o1;
    o0.x = h0 ? fmaxf(fmaf(di0, ax0, bx), 0.f) : 0.f;
    o0.y = h0 ? fmaxf(fmaf(di0, ay0, by), 0.f) : 0.f;
    o1.x = h1 ? fmaxf(fmaf(di1, ax1, bx), 0.f) : 0.f;
    o1.y = h1 ? fmaxf(fmaf(di1, ay1, by), 0.f) : 0.f;
    *(float2*)&agg[ln0][2 * lane] = o0;
    *(float2*)&agg[ln0 + 1][2 * lane] = o1;
  }
  __syncthreads();

  // ---- phase 2: (16-row, 8 valid) x 128 @ 128 x FOUT MFMA ----
  constexpr int NT = FOUT / 16;
  constexpr int KS = FIN / 32;
  constexpr int NTW = NT / 4;   // tiles per wave: FOUT=128 -> 2, FOUT=64 -> 1
  int q = lane >> 4, m = lane & 15;
  f32x4 acc[NTW];
#pragma unroll
  for (int tt = 0; tt < NTW; ++tt) acc[tt] = (f32x4){0.f, 0.f, 0.f, 0.f};
  const float* arow = &agg[m][0];
#pragma unroll
  for (int s = 0; s < KS; ++s) {
    float4 u0 = *(const float4*)(arow + s * 32 + q * 8);
    float4 u1 = *(const float4*)(arow + s * 32 + q * 8 + 4);
    float av[8];
    av[0] = u0.x; av[1] = u0.y; av[2] = u0.z; av[3] = u0.w;
    av[4] = u1.x; av[5] = u1.y; av[6] = u1.z; av[7] = u1.w;
    bf16x8 ahi, alo;
#pragma unroll
    for (int j = 0; j < 8; ++j) {
      ushort_t h = f2bf(av[j]);
      ahi[j] = (short)h;
      alo[j] = (short)f2bf(av[j] - bf2f(h));
    }
#pragma unroll
    for (int tt = 0; tt < NTW; ++tt) {
      int tg = wave * NTW + tt;
      size_t boff = (((size_t)tg * KS + s) * 64 + (size_t)lane) * 8;
      bf16x8 bh = *(const bf16x8*)(Bhi + boff);
      bf16x8 bl = *(const bf16x8*)(Blo + boff);
      acc[tt] = __builtin_amdgcn_mfma_f32_16x16x32_bf16(ahi, bh, acc[tt], 0, 0, 0);
      acc[tt] = __builtin_amdgcn_mfma_f32_16x16x32_bf16(alo, bh, acc[tt], 0, 0, 0);
      acc[tt] = __builtin_amdgcn_mfma_f32_16x16x32_bf16(ahi, bl, acc[tt], 0, 0, 0);
    }
  }
#pragma unroll
  for (int r = 0; r < 4; ++r) {
    int row = q * 4 + r;          // tile row; valid if < 8
    if (row >= NPB) continue;
    int orow = nb0 + row;
    if (orow >= n) continue;
    float sc = dinv[orow];
    ushort_t* trow = Tout + (size_t)orow * FOUT + m;
#pragma unroll
    for (int tt = 0; tt < NTW; ++tt)
      trow[(wave * NTW + tt) * 16] = f2bf(sc * acc[tt][r]);
  }
}

// ---------- CSR SpMM (final layer): out = dinv*(T'[d] + sum T'[c]) + b ----------
// T' rows bf16 pre-scaled. TWO destination nodes per wave.

template <int F, bool RELU, bool GD>
__global__ __launch_bounds__(256) void spmm_kernel(const ushort_t* __restrict__ t,
    const int* __restrict__ row_start, const int* __restrict__ deg,
    const int* __restrict__ col, const float* __restrict__ dinv,
    const float* __restrict__ bias, float* __restrict__ out, int n) {
  int gw = (int)((blockIdx.x * 256u + threadIdx.x) >> 6);
  int lane = threadIdx.x & 63;
  int n0 = gw * 2;
  int n1 = n0 + 1;
  if (n0 >= n) return;
  bool h1 = (n1 < n);
  int rs0 = row_start[n0], e0 = deg[n0] - 1;
  int rs1 = h1 ? row_start[n1] : 0, e1 = h1 ? (deg[n1] - 1) : 0;
  float di0 = dinv[n0];
  float di1 = h1 ? dinv[n1] : 0.f;

  if constexpr (F == 128) {
    uint_t s0 = ((const uint_t*)(t + (size_t)n0 * F))[lane];
    float ax0 = bf2f((ushort_t)(s0 & 0xFFFF)), ay0 = bf2f((ushort_t)(s0 >> 16));
    float ax1 = 0.f, ay1 = 0.f;
    if (h1) {
      uint_t s1 = ((const uint_t*)(t + (size_t)n1 * F))[lane];
      ax1 = bf2f((ushort_t)(s1 & 0xFFFF)); ay1 = bf2f((ushort_t)(s1 >> 16));
    }
    int p0 = rs0, q0 = rs0 + e0;
    int p1 = rs1, q1 = rs1 + e1;
    while (p0 + 4 <= q0 && p1 + 4 <= q1) {
      int c[8];
      uint_t v[8];
#pragma unroll
      for (int j = 0; j < 4; ++j) { c[j] = col[p0 + j]; c[4 + j] = col[p1 + j]; }
#pragma unroll
      for (int j = 0; j < 8; ++j) v[j] = ((const uint_t*)(t + (size_t)c[j] * F))[lane];
#pragma unroll
      for (int j = 0; j < 4; ++j) {
        ax0 += bf2f((ushort_t)(v[j] & 0xFFFF));
        ay0 += bf2f((ushort_t)(v[j] >> 16));
        ax1 += bf2f((ushort_t)(v[4 + j] & 0xFFFF));
        ay1 += bf2f((ushort_t)(v[4 + j] >> 16));
      }
      p0 += 4; p1 += 4;
    }
    for (; p0 + 4 <= q0; p0 += 4) {
      int c[4]; uint_t v[4];
#pragma unroll
      for (int j = 0; j < 4; ++j) c[j] = col[p0 + j];
#pragma unroll
      for (int j = 0; j < 4; ++j) v[j] = ((const uint_t*)(t + (size_t)c[j] * F))[lane];
#pragma unroll
      for (int j = 0; j < 4; ++j) {
        ax0 += bf2f((ushort_t)(v[j] & 0xFFFF)); ay0 += bf2f((ushort_t)(v[j] >> 16));
      }
    }
    for (; p0 < q0; ++p0) {
      uint_t v = ((const uint_t*)(t + (size_t)col[p0] * F))[lane];
      ax0 += bf2f((ushort_t)(v & 0xFFFF)); ay0 += bf2f((ushort_t)(v >> 16));
    }
    for (; p1 + 4 <= q1; p1 += 4) {
      int c[4]; uint_t v[4];
#pragma unroll
      for (int j = 0; j < 4; ++j) c[j] = col[p1 + j];
#pragma unroll
      for (int j = 0; j < 4; ++j) v[j] = ((const uint_t*)(t + (size_t)c[j] * F))[lane];
#pragma unroll
      for (int j = 0; j < 4; ++j) {
        ax1 += bf2f((ushort_t)(v[j] & 0xFFFF)); ay1 += bf2f((ushort_t)(v[j] >> 16));
      }
    }
    for (; p1 < q1; ++p1) {
      uint_t v = ((const uint_t*)(t + (size_t)col[p1] * F))[lane];
      ax1 += bf2f((ushort_t)(v & 0xFFFF)); ay1 += bf2f((ushort_t)(v >> 16));
    }
    float bx = bias[2 * lane], by = bias[2 * lane + 1];
    ax0 = fmaf(di0, ax0, bx); ay0 = fmaf(di0, ay0, by);
    if constexpr (RELU) { ax0 = fmaxf(ax0, 0.f); ay0 = fmaxf(ay0, 0.f); }
    float2 o0; o0.x = ax0; o0.y = ay0;
    ((float2*)(out + (size_t)n0 * F))[lane] = o0;
    if (h1) {
      ax1 = fmaf(di1, ax1, bx); ay1 = fmaf(di1, ay1, by);
      if constexpr (RELU) { ax1 = fmaxf(ax1, 0.f); ay1 = fmaxf(ay1, 0.f); }
      float2 o1; o1.x = ax1; o1.y = ay1;
      ((float2*)(out + (size_t)n1 * F))[lane] = o1;
    }
  } else {  // F == 64: one bf16 per lane
    float a0 = bf2f(t[(size_t)n0 * F + lane]);
    float a1 = h1 ? bf2f(t[(size_t)n1 * F + lane]) : 0.f;
    int p0 = rs0, q0 = rs0 + e0;
    int p1 = rs1, q1 = rs1 + e1;
    while (p0 + 4 <= q0 && p1 + 4 <= q1) {
      int c[8];
      ushort_t v[8];
#pragma unroll
      for (int j = 0; j < 4; ++j) { c[j] = col[p0 + j]; c[4 + j] = col[p1 + j]; }
#pragma unroll
      for (int j = 0; j < 8; ++j) v[j] = t[(size_t)c[j] * F + lane];
#pragma unroll
      for (int j = 0; j < 4; ++j) { a0 += bf2f(v[j]); a1 += bf2f(v[4 + j]); }
      p0 += 4; p1 += 4;
    }
    for (; p0 + 4 <= q0; p0 += 4) {
      int c[4]; ushort_t v[4];
#pragma unroll
      for (int j = 0; j < 4; ++j) c[j] = col[p0 + j];
#pragma unroll
      for (int j = 0; j < 4; ++j) v[j] = t[(size_t)c[j] * F + lane];
#pragma unroll
      for (int j = 0; j < 4; ++j) a0 += bf2f(v[j]);
    }
    for (; p0 < q0; ++p0) a0 += bf2f(t[(size_t)col[p0] * F + lane]);
    for (; p1 + 4 <= q1; p1 += 4) {
      int c[4]; ushort_t v[4];
#pragma unroll
      for (int j = 0; j < 4; ++j) c[j] = col[p1 + j];
#pragma unroll
      for (int j = 0; j < 4; ++j) v[j] = t[(size_t)c[j] * F + lane];
#pragma unroll
      for (int j = 0; j < 4; ++j) a1 += bf2f(v[j]);
    }
    for (; p1 < q1; ++p1) a1 += bf2f(t[(size_t)col[p1] * F + lane]);
    float b = bias[lane];
    a0 = fmaf(di0, a0, b);
    if constexpr (RELU) a0 = fmaxf(a0, 0.f);
    out[(size_t)n0 * F + lane] = a0;
    if (h1) {
      a1 = fmaf(di1, a1, b);
      if constexpr (RELU) a1 = fmaxf(a1, 0.f);
      out[(size_t)n1 * F + lane] = a1;
    }
  }
}

// ---------- launch ----------

extern "C" void kernel_launch(void* const* d_in, const int* in_sizes, int n_in,
                              void* d_out, int out_size, void* d_ws, size_t ws_size,
                              hipStream_t stream) {
  const float* x  = (const float*)d_in[0];
  const float* W1 = (const float*)d_in[1];
  const float* b1 = (const float*)d_in[2];
  const float* W2 = (const float*)d_in[3];
  const float* b2 = (const float*)d_in[4];
  const float* W3 = (const float*)d_in[5];
  const float* b3 = (const float*)d_in[6];
  const int* ei   = (const int*)d_in[7];  // harness delivers integers as int32

  int n = in_sizes[0] / DIN;
  int e = in_sizes[7] / 2;
  const int* src = ei;
  const int* dst = ei + e;

  char* ws = (char*)d_ws;
  size_t off = 0;
  auto alloc = [&](size_t bytes) -> void* {
    off = (off + 255) & ~(size_t)255;
    void* p = ws + off;
    off += bytes;
    return p;
  };
  int nbuckets = (n + 63) >> BSH;          // <= MAXB for n <= 65536
  int nbin = (e + EPB - 1) / EPB;

  int*      bucket_total = (int*)alloc((size_t)MAXB * 4);
  int*      bucket_base  = (int*)alloc((size_t)(MAXB + 1) * 4);
  int*      block_base   = (int*)alloc((size_t)nbin * nbuckets * 4);
  uint_t*   binned       = (uint_t*)alloc((size_t)e * 4);
  int*      deg          = (int*)alloc((size_t)n * 4);
  float*    dinv         = (float*)alloc((size_t)n * 4);
  int*      row_start    = (int*)alloc((size_t)n * 4);
  int*      col          = (int*)alloc((size_t)e * 4);
  ushort_t* Ta           = (ushort_t*)alloc((size_t)n * HID * 2);  // bf16 rows
  ushort_t* Tb           = (ushort_t*)alloc((size_t)n * HID * 2);  // bf16 rows
  ushort_t* W1hi         = (ushort_t*)alloc((size_t)DIN * HID * 2);
  ushort_t* W1lo         = (ushort_t*)alloc((size_t)DIN * HID * 2);
  ushort_t* W2hi         = (ushort_t*)alloc((size_t)HID * HID * 2);
  ushort_t* W2lo         = (ushort_t*)alloc((size_t)HID * HID * 2);
  ushort_t* W3hi         = (ushort_t*)alloc((size_t)HID * DOUT * 2);
  ushort_t* W3lo         = (ushort_t*)alloc((size_t)HID * DOUT * 2);
  (void)ws_size;

  int gemm_blocks = (n + 63) / 64;
  int sg_blocks = (n + 7) / 8;              // fused spmm_gemm: 8 nodes/block
  int nwaves = (n + 1) / 2;                 // 2 nodes per wave (final spmm)
  int spmm_blocks = (nwaves + 3) / 4;       // 4 waves per block
  constexpr int WPREP_TOTAL = DIN * HID + HID * HID + HID * DOUT;  // 57344
  int wblocks = (WPREP_TOTAL + 255) / 256;  // 224
  int iblocks = MAXB / 256;                 // 4

  initprep_kernel<<<iblocks + wblocks, 256, 0, stream>>>(
      bucket_total, iblocks,
      W1, W1hi, W1lo, W2, W2hi, W2lo, W3, W3hi, W3lo);
  bin_kernel<<<nbin, 256, 0, stream>>>(dst, e, nbuckets, bucket_total, block_base);
  scan_buckets_kernel<<<1, 256, 0, stream>>>(bucket_total, bucket_base, nbuckets);
  fusedA2_kernel<<<gemm_blocks + nbin, 256, 0, stream>>>(
      x, W1hi, W1lo, Ta, n, gemm_blocks,
      src, dst, bucket_base, block_base, binned, e, nbuckets);
  csr_kernel<<<nbuckets, 256, 0, stream>>>(binned, bucket_base, n, row_start, deg, dinv, col);

  // layer 1 agg + layer 2 GEMM (fused): Ta (unscaled, GD) -> Tb (scaled bf16)
  spmm_gemm_kernel<HID, true><<<sg_blocks, 256, 0, stream>>>(
      Ta, row_start, deg, col, dinv, b1, W2hi, W2lo, Tb, n);
  // layer 2 agg + layer 3 GEMM (fused): Tb -> Ta (n x 64, scaled bf16)
  spmm_gemm_kernel<DOUT, false><<<sg_blocks, 256, 0, stream>>>(
      Tb, row_start, deg, col, dinv, b2, W3hi, W3lo, Ta, n);
  // layer 3 agg (final): Ta -> out (fp32) + b3
  spmm_kernel<DOUT, false, false><<<spmm_blocks, 256, 0, stream>>>(
      Ta, row_start, deg, col, dinv, b3, (float*)d_out, n);
}